// Round 22
// baseline (299.146 us; speedup 1.0000x reference)
//
#include <hip/hip_runtime.h>
#include <math.h>

// ---------------------------------------------------------------------------
// RFSQDraftModelWithProjection — f32 in / f32 out, bf16 MFMA compute.
// r22: fix r21's OOB (grid-stride x-cvt: 2048 blocks x 8 chunk-iters, not 64).
// Everything else = r20/r21: BK=64 gemm64 (0 bank conflicts), xbf in d_out,
// split-K partials in G/d_out, fused reduceLN, fast GELU, 1 prep launch.
// ---------------------------------------------------------------------------

typedef unsigned short u16;
typedef __attribute__((ext_vector_type(8))) short bf16x8;
typedef __attribute__((ext_vector_type(4))) float f32x4;
typedef __attribute__((ext_vector_type(8))) unsigned short u16x8;
typedef __attribute__((ext_vector_type(4))) unsigned short u16x4;

__device__ __forceinline__ float bf2f(u16 u){
    union { unsigned int i; float f; } x; x.i = ((unsigned int)u) << 16; return x.f;
}
__device__ __forceinline__ u16 f2bf(float f){
    union { float f; unsigned int i; } x; x.f = f;
    unsigned int r = x.i + 0x7fffu + ((x.i >> 16) & 1u);
    return (u16)(r >> 16);
}
__device__ __forceinline__ float gelu_fast(float v){
    const float u = 1.5957691216f * v * (1.0f + 0.044715f * v * v);
    const float e = __expf(u);
    return v * (1.0f - 1.0f / (e + 1.0f));
}
#define GLOAD16(src, dst) __builtin_amdgcn_global_load_lds( \
    (const __attribute__((address_space(1))) void*)(src),   \
    (__attribute__((address_space(3))) void*)(dst), 16, 0, 0)
#define SCHED0 __builtin_amdgcn_sched_barrier(0)

// ---------------------------------------------------------------------------
// gemm64: C[M,N] = A[M,K] @ B[K,N] (+bias +res, opt GELU). 64x128 tile,
// BK=64, 4 waves, 16 MFMA/step, counted-vmcnt double buffer.
// LDS (row, c) holds global chunk (row, c ^ (row&7)); ds_read XORs the same.
// blockIdx.x = m-tile (XCD A-panel reuse), blockIdx.y = n-tile.
// A2/ksplit: concat A at k=ksplit (64 | ksplit).  PART: z = k-chunk
// (kch%64==0), f32 partials at Cout+z*czs.  Else z = batch via strides.
// ---------------------------------------------------------------------------
template<bool GELU, bool RES, bool OUTF32, bool PART>
__global__ __launch_bounds__(256) void gemm64(
    const u16* __restrict__ A, const u16* __restrict__ A2, int ksplit,
    const u16* __restrict__ Bt, const float* __restrict__ bias,
    const u16* __restrict__ res, int ldr,
    void* __restrict__ Cout, int K, int lda, int ldb, int ldc,
    long azs, long bzs, int biaszs, long czs, int kch)
{
    __shared__ __align__(16) u16 As[2][64 * 64];
    __shared__ __align__(16) u16 Bs[2][128 * 64];
    const int tid = threadIdx.x;
    const int w = tid >> 6, l = tid & 63;
    const int wr = w >> 1, wc = w & 1;
    const int m0 = blockIdx.x * 64, n0 = blockIdx.y * 128;
    const int z = blockIdx.z;
    int kbeg = 0, kend = K;
    if (PART) { kbeg = z * kch; kend = min(kbeg + kch, K); }
    const u16* A16 = A + (PART ? 0 : (size_t)z * azs);
    const u16* BtZ = Bt + (PART ? 0 : (size_t)z * bzs);
    const int swc = (l & 7) ^ (l >> 3);   // pre-swizzled source chunk

    f32x4 acc[2][4];
#pragma unroll
    for (int i = 0; i < 2; ++i)
#pragma unroll
        for (int j = 0; j < 4; ++j) acc[i][j] = (f32x4){0.f, 0.f, 0.f, 0.f};

    auto stageB = [&](int buf, int k0) {
#pragma unroll
        for (int j = 0; j < 4; ++j) {
            const int rb = w * 32 + j * 8;
            const u16* gb = BtZ + (size_t)(n0 + rb + (l >> 3)) * ldb + k0 + swc * 8;
            GLOAD16(gb, &Bs[buf][rb * 64]);
        }
    };
    auto stageA16 = [&](int buf, int k0) {
        const u16* base = (k0 >= ksplit) ? (A2 + (k0 - ksplit)) : (A16 + k0);
#pragma unroll
        for (int j = 0; j < 2; ++j) {
            const int rb = w * 16 + j * 8;
            const u16* ga = base + (size_t)(m0 + rb + (l >> 3)) * lda + swc * 8;
            GLOAD16(ga, &As[buf][rb * 64]);
        }
    };
    int cur = 0;
    auto compute = [&]() {
#pragma unroll
        for (int kk = 0; kk < 2; ++kk) {
            const int kcb = kk * 4 + (l >> 4);
            bf16x8 a[2], b[4];
#pragma unroll
            for (int i = 0; i < 2; ++i) {
                const int row = wr * 32 + i * 16 + (l & 15);
                a[i] = *(const bf16x8*)&As[cur][row * 64 + (kcb ^ (l & 7)) * 8];
            }
#pragma unroll
            for (int j = 0; j < 4; ++j) {
                const int row = wc * 64 + j * 16 + (l & 15);
                b[j] = *(const bf16x8*)&Bs[cur][row * 64 + (kcb ^ (l & 7)) * 8];
            }
#pragma unroll
            for (int i = 0; i < 2; ++i)
#pragma unroll
                for (int j = 0; j < 4; ++j)
                    acc[i][j] = __builtin_amdgcn_mfma_f32_16x16x32_bf16(a[i], b[j], acc[i][j], 0, 0, 0);
        }
    };

    const int nt = (kend - kbeg) >> 6;
    stageA16(0, kbeg);
    stageB(0, kbeg);
    for (int t = 0; t < nt; ++t) {
        const bool more = (t + 1) < nt;
        if (more) {
            const int kn = kbeg + ((t + 1) << 6);
            stageA16(cur ^ 1, kn);
            stageB(cur ^ 1, kn);
        }
        if (more) asm volatile("s_waitcnt vmcnt(6)" ::: "memory");
        else      asm volatile("s_waitcnt vmcnt(0)" ::: "memory");
        SCHED0;
        __builtin_amdgcn_s_barrier();
        SCHED0;
        compute();
        asm volatile("" ::: "memory");
        SCHED0;
        __builtin_amdgcn_s_barrier();
        SCHED0;
        cur ^= 1;
    }

    // epilogue: C/D layout col = l&15, row = (l>>4)*4 + r  [m89/m91]
    float* cF = (float*)Cout + (size_t)z * czs;
    u16*   cH = (u16*)Cout + (size_t)z * czs;
    const float* biasZ = (!PART && bias) ? bias + (size_t)z * biaszs : nullptr;
#pragma unroll
    for (int i = 0; i < 2; ++i) {
#pragma unroll
        for (int j = 0; j < 4; ++j) {
            const int col = n0 + wc * 64 + j * 16 + (l & 15);
            const int rowb = m0 + wr * 32 + i * 16 + (l >> 4) * 4;
#pragma unroll
            for (int r = 0; r < 4; ++r) {
                const int row = rowb + r;
                float v = acc[i][j][r];
                if (PART) {
                    cF[(size_t)row * ldc + col] = v;
                } else {
                    if (biasZ) v += biasZ[col];
                    if (RES) v += bf2f(res[(size_t)row * ldr + col]);
                    if (GELU) v = gelu_fast(v);
                    if (OUTF32) cF[(size_t)row * ldc + col] = v;
                    else        cH[(size_t)row * ldc + col] = f2bf(v);
                }
            }
        }
    }
}

// ---------------------------------------------------------------------------
// reduceLN512: fused split-K reduce + bias (+res) -> optional bf16 H-write,
// then row LayerNorm (512 cols) -> bf16 T-write. One wave per row.
// ---------------------------------------------------------------------------
template<int NP, bool RES, bool WRITEH>
__global__ __launch_bounds__(256) void reduceLN512(
    const float* __restrict__ part, long pzs, const float* __restrict__ bias,
    const u16* __restrict__ res, const float* __restrict__ g,
    const float* __restrict__ b, u16* __restrict__ outH, u16* __restrict__ outT)
{
    const int wid = threadIdx.x >> 6, l = threadIdx.x & 63;
    const size_t row = (size_t)blockIdx.x * 4 + wid;
    const size_t base = row * 512 + l * 8;
    float f[8];
    {
        const float4 p0 = *(const float4*)(part + base);
        const float4 p1 = *(const float4*)(part + base + 4);
        f[0]=p0.x; f[1]=p0.y; f[2]=p0.z; f[3]=p0.w;
        f[4]=p1.x; f[5]=p1.y; f[6]=p1.z; f[7]=p1.w;
    }
#pragma unroll
    for (int p = 1; p < NP; ++p) {
        const float4 p0 = *(const float4*)(part + (size_t)p * pzs + base);
        const float4 p1 = *(const float4*)(part + (size_t)p * pzs + base + 4);
        f[0]+=p0.x; f[1]+=p0.y; f[2]+=p0.z; f[3]+=p0.w;
        f[4]+=p1.x; f[5]+=p1.y; f[6]+=p1.z; f[7]+=p1.w;
    }
    {
        const float4 b0 = *(const float4*)(bias + l * 8);
        const float4 b1 = *(const float4*)(bias + l * 8 + 4);
        f[0]+=b0.x; f[1]+=b0.y; f[2]+=b0.z; f[3]+=b0.w;
        f[4]+=b1.x; f[5]+=b1.y; f[6]+=b1.z; f[7]+=b1.w;
    }
    if (RES) {
        const u16x8 r = *(const u16x8*)(res + base);
#pragma unroll
        for (int j = 0; j < 8; ++j) f[j] += bf2f(r[j]);
    }
    if (WRITEH) {
        u16x8 h;
#pragma unroll
        for (int j = 0; j < 8; ++j) h[j] = f2bf(f[j]);
        *(u16x8*)(outH + base) = h;
    }
    float s = 0.f, q = 0.f;
#pragma unroll
    for (int j = 0; j < 8; ++j) { s += f[j]; q += f[j] * f[j]; }
#pragma unroll
    for (int o = 32; o > 0; o >>= 1) { s += __shfl_xor(s, o); q += __shfl_xor(q, o); }
    const float mean = s * (1.f / 512.f);
    const float var = q * (1.f / 512.f) - mean * mean;
    const float rstd = rsqrtf(var + 1e-5f);
    u16x8 t;
#pragma unroll
    for (int j = 0; j < 8; ++j) {
        const int c = l * 8 + j;
        t[j] = f2bf((f[j] - mean) * rstd * g[c] + b[c]);
    }
    *(u16x8*)(outT + base) = t;
}

// per-head LN over 256 (rows are [8192,768], heads of 256), wave per (row,head)
__global__ __launch_bounds__(256) void lnh_kernel(
    const u16* __restrict__ in, const float* __restrict__ g,
    const float* __restrict__ b, u16* __restrict__ out)
{
    const int wid = threadIdx.x >> 6, l = threadIdx.x & 63;
    const int unit = blockIdx.x * 4 + wid;        // unit = h*8192 + row
    const int h = unit >> 13, row = unit & 8191;
    const size_t base = (size_t)row * 768 + h * 256 + l * 4;
    u16x4 v = *(const u16x4*)(in + base);
    float f[4], s = 0.f, q = 0.f;
#pragma unroll
    for (int j = 0; j < 4; ++j) { f[j] = bf2f(v[j]); s += f[j]; q += f[j] * f[j]; }
#pragma unroll
    for (int o = 32; o > 0; o >>= 1) { s += __shfl_xor(s, o); q += __shfl_xor(q, o); }
    const float mean = s * (1.f / 256.f);
    const float var = q * (1.f / 256.f) - mean * mean;
    const float rstd = rsqrtf(var + 1e-5f);
    u16x4 ov;
#pragma unroll
    for (int j = 0; j < 4; ++j) {
        const int c = h * 256 + l * 4 + j;
        ov[j] = f2bf((f[j] - mean) * rstd * g[c] + b[c]);
    }
    *(u16x4*)(out + base) = ov;
}

// ---------------------------------------------------------------------------
// prep_all (7976 blocks): bias first (latency hides under streaming);
// x-cvt as grid-stride streaming (2048 blocks x 8 chunk-iters = 16384 groups);
// Wh1t/Wh2t as per-head LDS-tile transposes.
// [0,8) bias | [,264) cvt wv_ca/wv_sa | [,2312) cvt x (grid-stride)
// | [,4360) w_inT | [,5384) wff1t | [,6408) wff2t | [,6664) woTca
// | [,6920) woTsa | [,7304) Wh1t | [,7976) Wh2t.
// ---------------------------------------------------------------------------
struct PrepPtrs {
    const float *x, *w_in, *w_ff1, *w_ff2, *wo_ca, *wo_sa, *wv_ca, *wv_sa;
    const float *wh1, *wh2, *b_in, *pos, *bv_sa, *bo_sa, *bv_ca, *bo_ca;
    u16 *xbf, *w_inT, *wff1t, *wff2t, *woT2, *wv2b, *Wh1t, *Wh2t;
    float *bias_in, *b_comb;
};

__device__ __forceinline__ void dev_cvt8(const float* src, u16* dst, int i)
{
    const float4* q = (const float4*)src + (size_t)i * 2;
    const float4 a = q[0], c = q[1];
    u16x8 v;
    v[0] = f2bf(a.x); v[1] = f2bf(a.y); v[2] = f2bf(a.z); v[3] = f2bf(a.w);
    v[4] = f2bf(c.x); v[5] = f2bf(c.y); v[6] = f2bf(c.z); v[7] = f2bf(c.w);
    *(u16x8*)(dst + (size_t)i * 8) = v;
}

__device__ __forceinline__ void dev_transpose(
    const float* in, u16* out, int K, int N, int t, int tid, u16 (*tile)[33])
{
    const int nt = N >> 5;
    const int n0 = (t % nt) * 32, k0 = (t / nt) * 32;
    const int tx = tid & 31, ty = tid >> 5;
#pragma unroll
    for (int i = 0; i < 32; i += 8)
        tile[ty + i][tx] = f2bf(in[(size_t)(k0 + ty + i) * N + (n0 + tx)]);
    __syncthreads();
#pragma unroll
    for (int i = 0; i < 32; i += 8)
        out[(size_t)(n0 + ty + i) * K + (k0 + tx)] = tile[tx][ty + i];
}

__global__ __launch_bounds__(256) void prep_all(PrepPtrs p)
{
    __shared__ u16 tile[32][33];
    __shared__ float psa[4][64], pca[4][64];
    const int tid = threadIdx.x;
    int b = blockIdx.x;
    if (b < 8) {   // bias prep (first: overlaps the streaming segments)
        const int ii = tid & 63, kg = tid >> 6;
        const int i = b * 64 + ii;
        float sa = 0.f, ca = 0.f;
#pragma unroll 4
        for (int k = kg; k < 512; k += 4) {
            sa += p.bv_sa[k] * p.wo_sa[(size_t)k * 512 + i];
            ca += p.bv_ca[k] * p.wo_ca[(size_t)k * 512 + i];
        }
        psa[kg][ii] = sa; pca[kg][ii] = ca;
        __syncthreads();
        if (kg == 0) {
            p.bias_in[i] = p.b_in[i] + p.pos[i];
            p.b_comb[i] = psa[0][ii] + psa[1][ii] + psa[2][ii] + psa[3][ii]
                        + pca[0][ii] + pca[1][ii] + pca[2][ii] + pca[3][ii]
                        + p.bo_sa[i] + p.bo_ca[i];
        }
        return;
    }
    b -= 8;
    if (b < 256) {
        if (b < 128) dev_cvt8(p.wv_ca, p.wv2b, b * 256 + tid);
        else         dev_cvt8(p.wv_sa, p.wv2b + 512 * 512, (b - 128) * 256 + tid);
        return;
    }
    b -= 256;
    if (b < 2048) {   // x -> bf16: 2048 blocks x 8 contiguous chunk-iters
#pragma unroll
        for (int it = 0; it < 8; ++it)
            dev_cvt8(p.x, p.xbf, (b * 8 + it) * 256 + tid);
        return;
    }
    b -= 2048;
    if (b < 2048) { dev_transpose(p.w_in, p.w_inT, 4096, 512, b, tid, tile); return; }
    b -= 2048;
    if (b < 1024) { dev_transpose(p.w_ff1, p.wff1t, 512, 2048, b, tid, tile); return; }
    b -= 1024;
    if (b < 1024) { dev_transpose(p.w_ff2, p.wff2t, 2048, 512, b, tid, tile); return; }
    b -= 1024;
    if (b < 256) { dev_transpose(p.wo_ca, p.woT2, 512, 512, b, tid, tile); return; }
    b -= 256;
    if (b < 256) { dev_transpose(p.wo_sa, p.woT2 + 512 * 512, 512, 512, b, tid, tile); return; }
    b -= 256;
    if (b < 384) {  // Wh1t: per-head transpose [512 d][256 k] -> [256 k][512 d]
        const int h = b / 128, t = b % 128;
        dev_transpose(p.wh1 + (size_t)h * 512 * 256,
                      p.Wh1t + (size_t)h * 256 * 512, 512, 256, t, tid, tile);
        return;
    }
    b -= 384;
    {   // Wh2t: per-head transpose [256 k][896 o] -> [896 o][256 k]
        const int h = b / 224, t = b % 224;
        dev_transpose(p.wh2 + (size_t)h * 256 * 896,
                      p.Wh2t + (size_t)h * 896 * 256, 256, 896, t, tid, tile);
    }
}

extern "C" void kernel_launch(void* const* d_in, const int* in_sizes, int n_in,
                              void* d_out, int out_size, void* d_ws, size_t ws_size,
                              hipStream_t stream)
{
    const float* ln1_g  = (const float*)d_in[4];
    const float* ln1_b  = (const float*)d_in[5];
    const float* ln3_g  = (const float*)d_in[16];
    const float* ln3_b  = (const float*)d_in[17];
    const float* b_ff1  = (const float*)d_in[19];
    const float* b_ff2  = (const float*)d_in[21];
    const float* lnoutg = (const float*)d_in[22];
    const float* lnoutb = (const float*)d_in[23];
    const float* bh1    = (const float*)d_in[25];
    const float* lnh_g  = (const float*)d_in[26];
    const float* lnh_b  = (const float*)d_in[27];
    const float* bh2    = (const float*)d_in[29];
    float* out = (float*)d_out;
    const int KBIG = 0x7fffffff;

    // ---- workspace layout (~70 MB, rewritten fully every call) ----
    char* wsp = (char*)d_ws;
    size_t off = 0;
    auto ALLOC = [&](size_t n) { char* r = wsp + off; off = (off + n + 255) & ~(size_t)255; return r; };
    u16* w_inT  = (u16*)ALLOC(512UL * 4096 * 2);
    u16* wff1t  = (u16*)ALLOC(2048UL * 512 * 2);
    u16* wff2t  = (u16*)ALLOC(512UL * 2048 * 2);
    u16* woT2   = (u16*)ALLOC(2UL * 512 * 512 * 2);
    u16* wv2b   = (u16*)ALLOC(2UL * 512 * 512 * 2);
    u16* Wct    = (u16*)ALLOC(512UL * 1024 * 2);
    u16* Wh1t   = (u16*)ALLOC(768UL * 512 * 2);
    u16* Wh2t   = (u16*)ALLOC(3UL * 896 * 256 * 2);
    float* bias_in = (float*)ALLOC(512 * 4);
    float* b_comb  = (float*)ALLOC(512 * 4);
    u16* h0   = (u16*)ALLOC(8192UL * 512 * 2);
    u16* T    = (u16*)ALLOC(8192UL * 512 * 2);
    u16* hbuf = (u16*)ALLOC(8192UL * 512 * 2);
    u16* G    = (u16*)ALLOC(8192UL * 2048 * 2);  // FF inter; partials; Z/Z2
    u16* Z  = G;
    u16* Z2 = (u16*)((char*)G + 8192UL * 768 * 2);
    // d_out (88 MB) lifetime: xbf [prep -> GEMM1], FF2 partials, final output
    u16*   xbf   = (u16*)d_out;                  // 8192x4096 bf16 = 67 MB
    float* partG = (float*)G;                    // GEMM1/attn partials x2
    float* partO = out;                          // FF2 partials x2
    const long PZS = 8192L * 512;

    // ---- consolidated prep (1 launch, includes x -> bf16) ----
    PrepPtrs pp;
    pp.x = (const float*)d_in[0];
    pp.w_in = (const float*)d_in[1];  pp.w_ff1 = (const float*)d_in[18];
    pp.w_ff2 = (const float*)d_in[20];
    pp.wo_ca = (const float*)d_in[14]; pp.wo_sa = (const float*)d_in[8];
    pp.wv_ca = (const float*)d_in[12]; pp.wv_sa = (const float*)d_in[6];
    pp.wh1 = (const float*)d_in[24];   pp.wh2 = (const float*)d_in[28];
    pp.b_in = (const float*)d_in[2];   pp.pos = (const float*)d_in[3];
    pp.bv_sa = (const float*)d_in[7];  pp.bo_sa = (const float*)d_in[9];
    pp.bv_ca = (const float*)d_in[13]; pp.bo_ca = (const float*)d_in[15];
    pp.xbf = xbf;
    pp.w_inT = w_inT; pp.wff1t = wff1t; pp.wff2t = wff2t;
    pp.woT2 = woT2; pp.wv2b = wv2b; pp.Wh1t = Wh1t; pp.Wh2t = Wh2t;
    pp.bias_in = bias_in; pp.b_comb = b_comb;
    prep_all<<<7976, 256, 0, stream>>>(pp);
    // Wct (z-batched): z=0 -> ca half (k<512), z=1 -> sa half (k>=512)
    gemm64<false, false, false, false><<<dim3(8, 4, 2), 256, 0, stream>>>(
        woT2, nullptr, KBIG, wv2b, nullptr, nullptr, 0, Wct,
        512, 512, 512, 1024, 512 * 512, 512 * 512, 0, 512, 0);

    // ---- main pipeline ----
    // GEMM1 (bf16 A = xbf) split-K x2 -> partials in G; fused reduce -> h0, T=ln1
    gemm64<false, false, false, true><<<dim3(128, 4, 2), 256, 0, stream>>>(
        xbf, nullptr, KBIG, w_inT, nullptr, nullptr, 0, partG,
        4096, 4096, 4096, 512, 0, 0, 0, PZS, 2048);
    reduceLN512<2, false, true><<<2048, 256, 0, stream>>>(
        partG, PZS, bias_in, nullptr, ln1_g, ln1_b, h0, T);
    // attention split-K x2: [h0 | T] @ Wct -> partials in G; fused reduce
    // +b_comb +h0 residual -> hbuf=h2, T=ln3
    gemm64<false, false, false, true><<<dim3(128, 4, 2), 256, 0, stream>>>(
        h0, T, 512, Wct, nullptr, nullptr, 0, partG,
        1024, 512, 1024, 512, 0, 0, 0, PZS, 512);
    reduceLN512<2, true, true><<<2048, 256, 0, stream>>>(
        partG, PZS, b_comb, h0, ln3_g, ln3_b, hbuf, T);
    // G = gelu(T @ w_ff1 + b_ff1)   [8192, 2048]
    gemm64<true, false, false, false><<<dim3(128, 16), 256, 0, stream>>>(
        T, nullptr, KBIG, wff1t, b_ff1, nullptr, 0, G,
        512, 512, 512, 2048, 0, 0, 0, 0, 0);
    // FF2 split-K x2 -> partials in d_out (xbf dead); fused reduce +b_ff2
    // +h2 residual -> T=lnout
    gemm64<false, false, false, true><<<dim3(128, 4, 2), 256, 0, stream>>>(
        G, nullptr, KBIG, wff2t, nullptr, nullptr, 0, partO,
        2048, 2048, 2048, 512, 0, 0, 0, PZS, 1024);
    reduceLN512<2, true, false><<<2048, 256, 0, stream>>>(
        partO, PZS, b_ff2, hbuf, lnoutg, lnoutb, nullptr, T);
    // Z = gelu(T @ Wh1 + bh1)   [8192, 768]
    gemm64<true, false, false, false><<<dim3(128, 6), 256, 0, stream>>>(
        T, nullptr, KBIG, Wh1t, bh1, nullptr, 0, Z,
        512, 512, 512, 768, 0, 0, 0, 0, 0);
    // Z2 = per-head LN(Z)
    lnh_kernel<<<6144, 256, 0, stream>>>(Z, lnh_g, lnh_b, Z2);
    // out[:, z*896:(z+1)*896] = Z2[:, z*256:+256] @ wh2[z] + bh2[z]
    // (f32, z-batched; overwrites ALL of d_out)
    gemm64<false, false, true, false><<<dim3(128, 7, 3), 256, 0, stream>>>(
        Z2, nullptr, KBIG, Wh2t, bh2, nullptr, 0, out,
        256, 768, 256, 2688, 256, 896 * 256, 896, 896, 0);
}

// Round 23
// 297.369 us; speedup vs baseline: 1.0060x; 1.0060x over previous
//
#include <hip/hip_runtime.h>
#include <math.h>

// ---------------------------------------------------------------------------
// RFSQDraftModelWithProjection — f32 in / f32 out, bf16 MFMA compute.
// r23 = r20 (best measured config, 297.2 us): BK=64 gemm64 (0 bank
// conflicts via both-sides XOR swizzle), xbf in d_out, split-K partials in
// G/d_out, fused reduceLN, fast GELU, single prep mega-kernel with bias
// first, x-cvt one-chunk-per-thread, per-head tile transposes.
// ---------------------------------------------------------------------------

typedef unsigned short u16;
typedef __attribute__((ext_vector_type(8))) short bf16x8;
typedef __attribute__((ext_vector_type(4))) float f32x4;
typedef __attribute__((ext_vector_type(8))) unsigned short u16x8;
typedef __attribute__((ext_vector_type(4))) unsigned short u16x4;

__device__ __forceinline__ float bf2f(u16 u){
    union { unsigned int i; float f; } x; x.i = ((unsigned int)u) << 16; return x.f;
}
__device__ __forceinline__ u16 f2bf(float f){
    union { float f; unsigned int i; } x; x.f = f;
    unsigned int r = x.i + 0x7fffu + ((x.i >> 16) & 1u);
    return (u16)(r >> 16);
}
__device__ __forceinline__ float gelu_fast(float v){
    const float u = 1.5957691216f * v * (1.0f + 0.044715f * v * v);
    const float e = __expf(u);
    return v * (1.0f - 1.0f / (e + 1.0f));
}
#define GLOAD16(src, dst) __builtin_amdgcn_global_load_lds( \
    (const __attribute__((address_space(1))) void*)(src),   \
    (__attribute__((address_space(3))) void*)(dst), 16, 0, 0)
#define SCHED0 __builtin_amdgcn_sched_barrier(0)

// ---------------------------------------------------------------------------
// gemm64: C[M,N] = A[M,K] @ B[K,N] (+bias +res, opt GELU). 64x128 tile,
// BK=64, 4 waves, 16 MFMA/step, counted-vmcnt double buffer.
// LDS (row, c) holds global chunk (row, c ^ (row&7)); ds_read XORs the same.
// blockIdx.x = m-tile (XCD A-panel reuse), blockIdx.y = n-tile.
// A2/ksplit: concat A at k=ksplit (64 | ksplit).  PART: z = k-chunk
// (kch%64==0), f32 partials at Cout+z*czs.  Else z = batch via strides.
// ---------------------------------------------------------------------------
template<bool GELU, bool RES, bool OUTF32, bool PART>
__global__ __launch_bounds__(256) void gemm64(
    const u16* __restrict__ A, const u16* __restrict__ A2, int ksplit,
    const u16* __restrict__ Bt, const float* __restrict__ bias,
    const u16* __restrict__ res, int ldr,
    void* __restrict__ Cout, int K, int lda, int ldb, int ldc,
    long azs, long bzs, int biaszs, long czs, int kch)
{
    __shared__ __align__(16) u16 As[2][64 * 64];
    __shared__ __align__(16) u16 Bs[2][128 * 64];
    const int tid = threadIdx.x;
    const int w = tid >> 6, l = tid & 63;
    const int wr = w >> 1, wc = w & 1;
    const int m0 = blockIdx.x * 64, n0 = blockIdx.y * 128;
    const int z = blockIdx.z;
    int kbeg = 0, kend = K;
    if (PART) { kbeg = z * kch; kend = min(kbeg + kch, K); }
    const u16* A16 = A + (PART ? 0 : (size_t)z * azs);
    const u16* BtZ = Bt + (PART ? 0 : (size_t)z * bzs);
    const int swc = (l & 7) ^ (l >> 3);   // pre-swizzled source chunk

    f32x4 acc[2][4];
#pragma unroll
    for (int i = 0; i < 2; ++i)
#pragma unroll
        for (int j = 0; j < 4; ++j) acc[i][j] = (f32x4){0.f, 0.f, 0.f, 0.f};

    auto stageB = [&](int buf, int k0) {
#pragma unroll
        for (int j = 0; j < 4; ++j) {
            const int rb = w * 32 + j * 8;
            const u16* gb = BtZ + (size_t)(n0 + rb + (l >> 3)) * ldb + k0 + swc * 8;
            GLOAD16(gb, &Bs[buf][rb * 64]);
        }
    };
    auto stageA16 = [&](int buf, int k0) {
        const u16* base = (k0 >= ksplit) ? (A2 + (k0 - ksplit)) : (A16 + k0);
#pragma unroll
        for (int j = 0; j < 2; ++j) {
            const int rb = w * 16 + j * 8;
            const u16* ga = base + (size_t)(m0 + rb + (l >> 3)) * lda + swc * 8;
            GLOAD16(ga, &As[buf][rb * 64]);
        }
    };
    int cur = 0;
    auto compute = [&]() {
#pragma unroll
        for (int kk = 0; kk < 2; ++kk) {
            const int kcb = kk * 4 + (l >> 4);
            bf16x8 a[2], b[4];
#pragma unroll
            for (int i = 0; i < 2; ++i) {
                const int row = wr * 32 + i * 16 + (l & 15);
                a[i] = *(const bf16x8*)&As[cur][row * 64 + (kcb ^ (l & 7)) * 8];
            }
#pragma unroll
            for (int j = 0; j < 4; ++j) {
                const int row = wc * 64 + j * 16 + (l & 15);
                b[j] = *(const bf16x8*)&Bs[cur][row * 64 + (kcb ^ (l & 7)) * 8];
            }
#pragma unroll
            for (int i = 0; i < 2; ++i)
#pragma unroll
                for (int j = 0; j < 4; ++j)
                    acc[i][j] = __builtin_amdgcn_mfma_f32_16x16x32_bf16(a[i], b[j], acc[i][j], 0, 0, 0);
        }
    };

    const int nt = (kend - kbeg) >> 6;
    stageA16(0, kbeg);
    stageB(0, kbeg);
    for (int t = 0; t < nt; ++t) {
        const bool more = (t + 1) < nt;
        if (more) {
            const int kn = kbeg + ((t + 1) << 6);
            stageA16(cur ^ 1, kn);
            stageB(cur ^ 1, kn);
        }
        if (more) asm volatile("s_waitcnt vmcnt(6)" ::: "memory");
        else      asm volatile("s_waitcnt vmcnt(0)" ::: "memory");
        SCHED0;
        __builtin_amdgcn_s_barrier();
        SCHED0;
        compute();
        asm volatile("" ::: "memory");
        SCHED0;
        __builtin_amdgcn_s_barrier();
        SCHED0;
        cur ^= 1;
    }

    // epilogue: C/D layout col = l&15, row = (l>>4)*4 + r  [m89/m91]
    float* cF = (float*)Cout + (size_t)z * czs;
    u16*   cH = (u16*)Cout + (size_t)z * czs;
    const float* biasZ = (!PART && bias) ? bias + (size_t)z * biaszs : nullptr;
#pragma unroll
    for (int i = 0; i < 2; ++i) {
#pragma unroll
        for (int j = 0; j < 4; ++j) {
            const int col = n0 + wc * 64 + j * 16 + (l & 15);
            const int rowb = m0 + wr * 32 + i * 16 + (l >> 4) * 4;
#pragma unroll
            for (int r = 0; r < 4; ++r) {
                const int row = rowb + r;
                float v = acc[i][j][r];
                if (PART) {
                    cF[(size_t)row * ldc + col] = v;
                } else {
                    if (biasZ) v += biasZ[col];
                    if (RES) v += bf2f(res[(size_t)row * ldr + col]);
                    if (GELU) v = gelu_fast(v);
                    if (OUTF32) cF[(size_t)row * ldc + col] = v;
                    else        cH[(size_t)row * ldc + col] = f2bf(v);
                }
            }
        }
    }
}

// ---------------------------------------------------------------------------
// reduceLN512: fused split-K reduce + bias (+res) -> optional bf16 H-write,
// then row LayerNorm (512 cols) -> bf16 T-write. One wave per row.
// ---------------------------------------------------------------------------
template<int NP, bool RES, bool WRITEH>
__global__ __launch_bounds__(256) void reduceLN512(
    const float* __restrict__ part, long pzs, const float* __restrict__ bias,
    const u16* __restrict__ res, const float* __restrict__ g,
    const float* __restrict__ b, u16* __restrict__ outH, u16* __restrict__ outT)
{
    const int wid = threadIdx.x >> 6, l = threadIdx.x & 63;
    const size_t row = (size_t)blockIdx.x * 4 + wid;
    const size_t base = row * 512 + l * 8;
    float f[8];
    {
        const float4 p0 = *(const float4*)(part + base);
        const float4 p1 = *(const float4*)(part + base + 4);
        f[0]=p0.x; f[1]=p0.y; f[2]=p0.z; f[3]=p0.w;
        f[4]=p1.x; f[5]=p1.y; f[6]=p1.z; f[7]=p1.w;
    }
#pragma unroll
    for (int p = 1; p < NP; ++p) {
        const float4 p0 = *(const float4*)(part + (size_t)p * pzs + base);
        const float4 p1 = *(const float4*)(part + (size_t)p * pzs + base + 4);
        f[0]+=p0.x; f[1]+=p0.y; f[2]+=p0.z; f[3]+=p0.w;
        f[4]+=p1.x; f[5]+=p1.y; f[6]+=p1.z; f[7]+=p1.w;
    }
    {
        const float4 b0 = *(const float4*)(bias + l * 8);
        const float4 b1 = *(const float4*)(bias + l * 8 + 4);
        f[0]+=b0.x; f[1]+=b0.y; f[2]+=b0.z; f[3]+=b0.w;
        f[4]+=b1.x; f[5]+=b1.y; f[6]+=b1.z; f[7]+=b1.w;
    }
    if (RES) {
        const u16x8 r = *(const u16x8*)(res + base);
#pragma unroll
        for (int j = 0; j < 8; ++j) f[j] += bf2f(r[j]);
    }
    if (WRITEH) {
        u16x8 h;
#pragma unroll
        for (int j = 0; j < 8; ++j) h[j] = f2bf(f[j]);
        *(u16x8*)(outH + base) = h;
    }
    float s = 0.f, q = 0.f;
#pragma unroll
    for (int j = 0; j < 8; ++j) { s += f[j]; q += f[j] * f[j]; }
#pragma unroll
    for (int o = 32; o > 0; o >>= 1) { s += __shfl_xor(s, o); q += __shfl_xor(q, o); }
    const float mean = s * (1.f / 512.f);
    const float var = q * (1.f / 512.f) - mean * mean;
    const float rstd = rsqrtf(var + 1e-5f);
    u16x8 t;
#pragma unroll
    for (int j = 0; j < 8; ++j) {
        const int c = l * 8 + j;
        t[j] = f2bf((f[j] - mean) * rstd * g[c] + b[c]);
    }
    *(u16x8*)(outT + base) = t;
}

// per-head LN over 256 (rows are [8192,768], heads of 256), wave per (row,head)
__global__ __launch_bounds__(256) void lnh_kernel(
    const u16* __restrict__ in, const float* __restrict__ g,
    const float* __restrict__ b, u16* __restrict__ out)
{
    const int wid = threadIdx.x >> 6, l = threadIdx.x & 63;
    const int unit = blockIdx.x * 4 + wid;        // unit = h*8192 + row
    const int h = unit >> 13, row = unit & 8191;
    const size_t base = (size_t)row * 768 + h * 256 + l * 4;
    u16x4 v = *(const u16x4*)(in + base);
    float f[4], s = 0.f, q = 0.f;
#pragma unroll
    for (int j = 0; j < 4; ++j) { f[j] = bf2f(v[j]); s += f[j]; q += f[j] * f[j]; }
#pragma unroll
    for (int o = 32; o > 0; o >>= 1) { s += __shfl_xor(s, o); q += __shfl_xor(q, o); }
    const float mean = s * (1.f / 256.f);
    const float var = q * (1.f / 256.f) - mean * mean;
    const float rstd = rsqrtf(var + 1e-5f);
    u16x4 ov;
#pragma unroll
    for (int j = 0; j < 4; ++j) {
        const int c = h * 256 + l * 4 + j;
        ov[j] = f2bf((f[j] - mean) * rstd * g[c] + b[c]);
    }
    *(u16x4*)(out + base) = ov;
}

// ---------------------------------------------------------------------------
// prep_all (22312 blocks): bias-prep FIRST (latency hides under streaming);
// x-cvt one-chunk-per-thread (16384 blocks); Wh1t/Wh2t per-head transposes.
// [0,8) bias | [,264) cvt wv_ca/wv_sa | [,16648) cvt x | [,18696) w_inT
// | [,19720) wff1t | [,20744) wff2t | [,21000) woTca | [,21256) woTsa
// | [,21640) Wh1t (3x128 tiles) | [,22312) Wh2t (3x224 tiles).
// ---------------------------------------------------------------------------
struct PrepPtrs {
    const float *x, *w_in, *w_ff1, *w_ff2, *wo_ca, *wo_sa, *wv_ca, *wv_sa;
    const float *wh1, *wh2, *b_in, *pos, *bv_sa, *bo_sa, *bv_ca, *bo_ca;
    u16 *xbf, *w_inT, *wff1t, *wff2t, *woT2, *wv2b, *Wh1t, *Wh2t;
    float *bias_in, *b_comb;
};

__device__ __forceinline__ void dev_cvt8(const float* src, u16* dst, int i)
{
    const float4* q = (const float4*)src + (size_t)i * 2;
    const float4 a = q[0], c = q[1];
    u16x8 v;
    v[0] = f2bf(a.x); v[1] = f2bf(a.y); v[2] = f2bf(a.z); v[3] = f2bf(a.w);
    v[4] = f2bf(c.x); v[5] = f2bf(c.y); v[6] = f2bf(c.z); v[7] = f2bf(c.w);
    *(u16x8*)(dst + (size_t)i * 8) = v;
}

__device__ __forceinline__ void dev_transpose(
    const float* in, u16* out, int K, int N, int t, int tid, u16 (*tile)[33])
{
    const int nt = N >> 5;
    const int n0 = (t % nt) * 32, k0 = (t / nt) * 32;
    const int tx = tid & 31, ty = tid >> 5;
#pragma unroll
    for (int i = 0; i < 32; i += 8)
        tile[ty + i][tx] = f2bf(in[(size_t)(k0 + ty + i) * N + (n0 + tx)]);
    __syncthreads();
#pragma unroll
    for (int i = 0; i < 32; i += 8)
        out[(size_t)(n0 + ty + i) * K + (k0 + tx)] = tile[tx][ty + i];
}

__global__ __launch_bounds__(256) void prep_all(PrepPtrs p)
{
    __shared__ u16 tile[32][33];
    __shared__ float psa[4][64], pca[4][64];
    const int tid = threadIdx.x;
    int b = blockIdx.x;
    if (b < 8) {   // bias prep (first: overlaps the streaming segments)
        const int ii = tid & 63, kg = tid >> 6;
        const int i = b * 64 + ii;
        float sa = 0.f, ca = 0.f;
#pragma unroll 4
        for (int k = kg; k < 512; k += 4) {
            sa += p.bv_sa[k] * p.wo_sa[(size_t)k * 512 + i];
            ca += p.bv_ca[k] * p.wo_ca[(size_t)k * 512 + i];
        }
        psa[kg][ii] = sa; pca[kg][ii] = ca;
        __syncthreads();
        if (kg == 0) {
            p.bias_in[i] = p.b_in[i] + p.pos[i];
            p.b_comb[i] = psa[0][ii] + psa[1][ii] + psa[2][ii] + psa[3][ii]
                        + pca[0][ii] + pca[1][ii] + pca[2][ii] + pca[3][ii]
                        + p.bo_sa[i] + p.bo_ca[i];
        }
        return;
    }
    b -= 8;
    if (b < 256) {
        if (b < 128) dev_cvt8(p.wv_ca, p.wv2b, b * 256 + tid);
        else         dev_cvt8(p.wv_sa, p.wv2b + 512 * 512, (b - 128) * 256 + tid);
        return;
    }
    b -= 256;
    if (b < 16384) { dev_cvt8(p.x, p.xbf, b * 256 + tid); return; }
    b -= 16384;
    if (b < 2048) { dev_transpose(p.w_in, p.w_inT, 4096, 512, b, tid, tile); return; }
    b -= 2048;
    if (b < 1024) { dev_transpose(p.w_ff1, p.wff1t, 512, 2048, b, tid, tile); return; }
    b -= 1024;
    if (b < 1024) { dev_transpose(p.w_ff2, p.wff2t, 2048, 512, b, tid, tile); return; }
    b -= 1024;
    if (b < 256) { dev_transpose(p.wo_ca, p.woT2, 512, 512, b, tid, tile); return; }
    b -= 256;
    if (b < 256) { dev_transpose(p.wo_sa, p.woT2 + 512 * 512, 512, 512, b, tid, tile); return; }
    b -= 256;
    if (b < 384) {  // Wh1t: per-head transpose [512 d][256 k] -> [256 k][512 d]
        const int h = b / 128, t = b % 128;
        dev_transpose(p.wh1 + (size_t)h * 512 * 256,
                      p.Wh1t + (size_t)h * 256 * 512, 512, 256, t, tid, tile);
        return;
    }
    b -= 384;
    {   // Wh2t: per-head transpose [256 k][896 o] -> [896 o][256 k]
        const int h = b / 224, t = b % 224;
        dev_transpose(p.wh2 + (size_t)h * 256 * 896,
                      p.Wh2t + (size_t)h * 896 * 256, 256, 896, t, tid, tile);
    }
}

extern "C" void kernel_launch(void* const* d_in, const int* in_sizes, int n_in,
                              void* d_out, int out_size, void* d_ws, size_t ws_size,
                              hipStream_t stream)
{
    const float* ln1_g  = (const float*)d_in[4];
    const float* ln1_b  = (const float*)d_in[5];
    const float* ln3_g  = (const float*)d_in[16];
    const float* ln3_b  = (const float*)d_in[17];
    const float* b_ff1  = (const float*)d_in[19];
    const float* b_ff2  = (const float*)d_in[21];
    const float* lnoutg = (const float*)d_in[22];
    const float* lnoutb = (const float*)d_in[23];
    const float* bh1    = (const float*)d_in[25];
    const float* lnh_g  = (const float*)d_in[26];
    const float* lnh_b  = (const float*)d_in[27];
    const float* bh2    = (const float*)d_in[29];
    float* out = (float*)d_out;
    const int KBIG = 0x7fffffff;

    // ---- workspace layout (~70 MB, rewritten fully every call) ----
    char* wsp = (char*)d_ws;
    size_t off = 0;
    auto ALLOC = [&](size_t n) { char* r = wsp + off; off = (off + n + 255) & ~(size_t)255; return r; };
    u16* w_inT  = (u16*)ALLOC(512UL * 4096 * 2);
    u16* wff1t  = (u16*)ALLOC(2048UL * 512 * 2);
    u16* wff2t  = (u16*)ALLOC(512UL * 2048 * 2);
    u16* woT2   = (u16*)ALLOC(2UL * 512 * 512 * 2);
    u16* wv2b   = (u16*)ALLOC(2UL * 512 * 512 * 2);
    u16* Wct    = (u16*)ALLOC(512UL * 1024 * 2);
    u16* Wh1t   = (u16*)ALLOC(768UL * 512 * 2);
    u16* Wh2t   = (u16*)ALLOC(3UL * 896 * 256 * 2);
    float* bias_in = (float*)ALLOC(512 * 4);
    float* b_comb  = (float*)ALLOC(512 * 4);
    u16* h0   = (u16*)ALLOC(8192UL * 512 * 2);
    u16* T    = (u16*)ALLOC(8192UL * 512 * 2);
    u16* hbuf = (u16*)ALLOC(8192UL * 512 * 2);
    u16* G    = (u16*)ALLOC(8192UL * 2048 * 2);  // FF inter; partials; Z/Z2
    u16* Z  = G;
    u16* Z2 = (u16*)((char*)G + 8192UL * 768 * 2);
    // d_out (88 MB) lifetime: xbf [prep -> GEMM1], FF2 partials, final output
    u16*   xbf   = (u16*)d_out;                  // 8192x4096 bf16 = 67 MB
    float* partG = (float*)G;                    // GEMM1/attn partials x2
    float* partO = out;                          // FF2 partials x2
    const long PZS = 8192L * 512;

    // ---- consolidated prep (1 launch, includes x -> bf16) ----
    PrepPtrs pp;
    pp.x = (const float*)d_in[0];
    pp.w_in = (const float*)d_in[1];  pp.w_ff1 = (const float*)d_in[18];
    pp.w_ff2 = (const float*)d_in[20];
    pp.wo_ca = (const float*)d_in[14]; pp.wo_sa = (const float*)d_in[8];
    pp.wv_ca = (const float*)d_in[12]; pp.wv_sa = (const float*)d_in[6];
    pp.wh1 = (const float*)d_in[24];   pp.wh2 = (const float*)d_in[28];
    pp.b_in = (const float*)d_in[2];   pp.pos = (const float*)d_in[3];
    pp.bv_sa = (const float*)d_in[7];  pp.bo_sa = (const float*)d_in[9];
    pp.bv_ca = (const float*)d_in[13]; pp.bo_ca = (const float*)d_in[15];
    pp.xbf = xbf;
    pp.w_inT = w_inT; pp.wff1t = wff1t; pp.wff2t = wff2t;
    pp.woT2 = woT2; pp.wv2b = wv2b; pp.Wh1t = Wh1t; pp.Wh2t = Wh2t;
    pp.bias_in = bias_in; pp.b_comb = b_comb;
    prep_all<<<22312, 256, 0, stream>>>(pp);
    // Wct (z-batched): z=0 -> ca half (k<512), z=1 -> sa half (k>=512)
    gemm64<false, false, false, false><<<dim3(8, 4, 2), 256, 0, stream>>>(
        woT2, nullptr, KBIG, wv2b, nullptr, nullptr, 0, Wct,
        512, 512, 512, 1024, 512 * 512, 512 * 512, 0, 512, 0);

    // ---- main pipeline ----
    // GEMM1 (bf16 A = xbf) split-K x2 -> partials in G; fused reduce -> h0, T=ln1
    gemm64<false, false, false, true><<<dim3(128, 4, 2), 256, 0, stream>>>(
        xbf, nullptr, KBIG, w_inT, nullptr, nullptr, 0, partG,
        4096, 4096, 4096, 512, 0, 0, 0, PZS, 2048);
    reduceLN512<2, false, true><<<2048, 256, 0, stream>>>(
        partG, PZS, bias_in, nullptr, ln1_g, ln1_b, h0, T);
    // attention split-K x2: [h0 | T] @ Wct -> partials in G; fused reduce
    // +b_comb +h0 residual -> hbuf=h2, T=ln3
    gemm64<false, false, false, true><<<dim3(128, 4, 2), 256, 0, stream>>>(
        h0, T, 512, Wct, nullptr, nullptr, 0, partG,
        1024, 512, 1024, 512, 0, 0, 0, PZS, 512);
    reduceLN512<2, true, true><<<2048, 256, 0, stream>>>(
        partG, PZS, b_comb, h0, ln3_g, ln3_b, hbuf, T);
    // G = gelu(T @ w_ff1 + b_ff1)   [8192, 2048]
    gemm64<true, false, false, false><<<dim3(128, 16), 256, 0, stream>>>(
        T, nullptr, KBIG, wff1t, b_ff1, nullptr, 0, G,
        512, 512, 512, 2048, 0, 0, 0, 0, 0);
    // FF2 split-K x2 -> partials in d_out (xbf dead); fused reduce +b_ff2
    // +h2 residual -> T=lnout
    gemm64<false, false, false, true><<<dim3(128, 4, 2), 256, 0, stream>>>(
        G, nullptr, KBIG, wff2t, nullptr, nullptr, 0, partO,
        2048, 2048, 2048, 512, 0, 0, 0, PZS, 1024);
    reduceLN512<2, true, false><<<2048, 256, 0, stream>>>(
        partO, PZS, b_ff2, hbuf, lnoutg, lnoutb, nullptr, T);
    // Z = gelu(T @ Wh1 + bh1)   [8192, 768]
    gemm64<true, false, false, false><<<dim3(128, 6), 256, 0, stream>>>(
        T, nullptr, KBIG, Wh1t, bh1, nullptr, 0, Z,
        512, 512, 512, 768, 0, 0, 0, 0, 0);
    // Z2 = per-head LN(Z)
    lnh_kernel<<<6144, 256, 0, stream>>>(Z, lnh_g, lnh_b, Z2);
    // out[:, z*896:(z+1)*896] = Z2[:, z*256:+256] @ wh2[z] + bh2[z]
    // (f32, z-batched; overwrites ALL of d_out)
    gemm64<false, false, true, false><<<dim3(128, 7, 3), 256, 0, stream>>>(
        Z2, nullptr, KBIG, Wh2t, bh2, nullptr, 0, out,
        256, 768, 256, 2688, 256, 896 * 256, 896, 896, 0);
}